// Round 1
// baseline (154.967 us; speedup 1.0000x reference)
//
#include <hip/hip_runtime.h>

// PointWarping: B=2, C=3, N=8192. Brute-force K=3 NN + inverse-distance flow interp.
// 8 threads per query, 32 queries/block, candidate tiles staged in LDS as float4.

#define NPTS   8192
#define TILE   2048
#define NTILES (NPTS / TILE)
#define GROUP  8
#define BLOCK  256
#define QPB    (BLOCK / GROUP)   // 32 queries per block
#define EPSV   1e-10f

__global__ __launch_bounds__(BLOCK, 2)
void pointwarp_kernel(const float* __restrict__ xyz1,
                      const float* __restrict__ xyz2,
                      const float* __restrict__ flow1,
                      float* __restrict__ out) {
    __shared__ float4 s_pts[TILE];              // 32 KB: candidate x,y,z,pad
    __shared__ float  s_md[QPB * GROUP * 3];    // 3 KB: partial top-3 dists
    __shared__ int    s_mi[QPB * GROUP * 3];    // 3 KB: partial top-3 idxs

    const int tid = threadIdx.x;
    const int g   = tid >> 3;              // query slot within block [0,32)
    const int t   = tid & (GROUP - 1);     // lane within query group [0,8)
    const int blocksPerBatch = NPTS / QPB; // 256
    const int b   = blockIdx.x / blocksPerBatch;
    const int n2  = (blockIdx.x % blocksPerBatch) * QPB + g;

    const float* x1 = xyz1 + (size_t)b * 3 * NPTS;
    const float* x2 = xyz2 + (size_t)b * 3 * NPTS;
    const float* f1 = flow1 + (size_t)b * 3 * NPTS;

    const float qx = x2[0 * NPTS + n2];
    const float qy = x2[1 * NPTS + n2];
    const float qz = x2[2 * NPTS + n2];

    // running top-3 smallest squared distances (d0 <= d1 <= d2) + indices
    float d0 = 1e30f, d1 = 1e30f, d2 = 1e30f;
    int   i0 = 0, i1 = 0, i2 = 0;

    for (int tile = 0; tile < NTILES; ++tile) {
        const int base = tile * TILE;
        // cooperative stage: xyz1 + flow1 -> LDS (coalesced reads)
        for (int j = tid; j < TILE; j += BLOCK) {
            const int n1 = base + j;
            const float px = x1[0 * NPTS + n1] + f1[0 * NPTS + n1];
            const float py = x1[1 * NPTS + n1] + f1[1 * NPTS + n1];
            const float pz = x1[2 * NPTS + n1] + f1[2 * NPTS + n1];
            s_pts[j] = make_float4(px, py, pz, 0.0f);
        }
        __syncthreads();

        // scan: thread t covers within-tile indices j*8+t (bank-disjoint b128 reads)
        #pragma unroll 4
        for (int j = 0; j < TILE / GROUP; ++j) {
            const int jj = j * GROUP + t;
            const float4 p = s_pts[jj];
            const float dx = p.x - qx;
            const float dy = p.y - qy;
            const float dz = p.z - qz;
            const float d = dx * dx + dy * dy + dz * dz;
            if (d < d2) {                       // rare in steady state
                const int idx = base + jj;
                const bool c1 = d < d1;
                const bool c0 = d < d0;
                d2 = c1 ? d1 : d;
                i2 = c1 ? i1 : idx;
                d1 = c0 ? d0 : (c1 ? d : d1);
                i1 = c0 ? i0 : (c1 ? idx : i1);
                d0 = c0 ? d : d0;
                i0 = c0 ? idx : i0;
            }
        }
        __syncthreads();
    }

    // publish per-thread partial top-3
    const int mb = tid * 3;
    s_md[mb + 0] = d0; s_mi[mb + 0] = i0;
    s_md[mb + 1] = d1; s_mi[mb + 1] = i1;
    s_md[mb + 2] = d2; s_mi[mb + 2] = i2;
    __syncthreads();

    if (t == 0) {
        // merge the 8 partial top-3 lists (24 entries) for this query
        float e0 = 1e30f, e1 = 1e30f, e2 = 1e30f;
        int   j0 = 0, j1 = 0, j2 = 0;
        const int s = g * GROUP * 3;
        for (int k = 0; k < GROUP * 3; ++k) {
            const float d = s_md[s + k];
            const int idx = s_mi[s + k];
            if (d < e2) {
                const bool c1 = d < e1;
                const bool c0 = d < e0;
                e2 = c1 ? e1 : d;
                j2 = c1 ? j1 : idx;
                e1 = c0 ? e0 : (c1 ? d : e1);
                j1 = c0 ? j0 : (c1 ? idx : j1);
                e0 = c0 ? d : e0;
                j0 = c0 ? idx : j0;
            }
        }
        // inverse-distance weights (sqrt only here, selection was on d^2)
        float w0 = 1.0f / fmaxf(sqrtf(e0), EPSV);
        float w1 = 1.0f / fmaxf(sqrtf(e1), EPSV);
        float w2 = 1.0f / fmaxf(sqrtf(e2), EPSV);
        const float ws = w0 + w1 + w2;
        w0 /= ws; w1 /= ws; w2 /= ws;

        float* o = out + (size_t)b * 3 * NPTS;
        #pragma unroll
        for (int c = 0; c < 3; ++c) {
            const float fl = w0 * f1[c * NPTS + j0]
                           + w1 * f1[c * NPTS + j1]
                           + w2 * f1[c * NPTS + j2];
            o[c * NPTS + n2] = x2[c * NPTS + n2] - fl;
        }
    }
}

extern "C" void kernel_launch(void* const* d_in, const int* in_sizes, int n_in,
                              void* d_out, int out_size, void* d_ws, size_t ws_size,
                              hipStream_t stream) {
    const float* xyz1  = (const float*)d_in[0];
    const float* xyz2  = (const float*)d_in[1];
    const float* flow1 = (const float*)d_in[2];
    float* out = (float*)d_out;

    const int B = in_sizes[0] / (3 * NPTS);     // = 2
    const int grid = B * (NPTS / QPB);          // 512 blocks
    pointwarp_kernel<<<grid, BLOCK, 0, stream>>>(xyz1, xyz2, flow1, out);
}